// Round 8
// baseline (257.067 us; speedup 1.0000x reference)
//
#include <hip/hip_runtime.h>
#include <stdint.h>

#define G_   250
#define P_   200
#define EPG  3200
#define E_   800000
#define F_   128
#define R_   8
#define HROW 136   // f16 elems per row; 272 B stride, 16B-aligned rows
#define NKEY (R_ * P_)   // 1600 (rel,dst) buckets
#define WFRAG_ELEMS (2 * 9 * 8 * 4 * 64 * 8)   // 294912

typedef _Float16 f16x8 __attribute__((ext_vector_type(8)));
typedef _Float16 f16x4 __attribute__((ext_vector_type(4)));
typedef float    f32x4 __attribute__((ext_vector_type(4)));
typedef float    f32x16 __attribute__((ext_vector_type(16)));

// ---------------- single fused kernel: wstage + CSR + msg + both RGCN layers + scoring --------
// One workgroup = one graph (250 blocks, 1/CU -> all co-resident; safe spin barrier).
__global__ __launch_bounds__(512, 2) void k_main(
    const float* __restrict__ x, const int* __restrict__ ei, const int* __restrict__ et,
    const float* __restrict__ W1, const float* __restrict__ root1,
    const float* __restrict__ W2, const float* __restrict__ root2,
    const float* __restrict__ b1, const float* __restrict__ b2,
    const float* __restrict__ message, const float* __restrict__ embed,
    const float* __restrict__ cw, const float* __restrict__ cb,
    const float* __restrict__ mw, const float* __restrict__ mb,
    _Float16* __restrict__ wf, uint32_t* __restrict__ wcnt,
    float* __restrict__ out) {
  __shared__ __attribute__((aligned(16))) _Float16 hbuf0[P_ * HROW];  // 54400 B (x / layer-1 in)
  __shared__ __attribute__((aligned(16))) _Float16 hbuf1[P_ * HROW];  // 54400 B (h' / layer-2 in)
  __shared__ unsigned short csrS[EPG];                                // 6400 B
  __shared__ int offsS[NKEY + 1];                                     // 6404 B
  __shared__ float msgS[F_ + 1];                                      // 516 B  -> ~122.1 KB

  int g = blockIdx.x, tid = threadIdx.x;
  int lane = tid & 63, wave = tid >> 6;
  int m32 = lane & 31, kh = lane >> 5;

  // ---- phase W: generate this block's wfrag slice (B-frag layout for mfma_f32_32x32x16_f16)
  // flat = ((((l*9+r)*8 + kt)*4 + ntj)*64 + lane)*8 + j ;
  // value = W[r][k = kt*16 + (lane>>5)*8 + j][n = ntj*32 + (lane&31)]  (r==8 -> root)
  for (int i = g * 512 + tid; i < WFRAG_ELEMS; i += G_ * 512) {
    int n = i & 127;
    int k = (i >> 7) & 127;
    int rl_ = i >> 14;          // 0..17
    int r = rl_ % 9, l = rl_ / 9;
    const float* Wl = (l == 0) ? W1 : W2;
    const float* rt = (l == 0) ? root1 : root2;
    float v = (r < 8) ? Wl[(r * F_ + k) * F_ + n] : rt[k * F_ + n];
    int lane2 = (n & 31) | (((k >> 3) & 1) << 5);
    int j = k & 7, kt = k >> 4, ntj = n >> 5;
    wf[((((l * 9 + r) * 8 + kt) * 4 + ntj) * 64 + lane2) * 8 + j] = (_Float16)v;
  }
  __threadfence();
  __syncthreads();
  if (tid == 0) atomicAdd(wcnt, 1u);   // arrive (ws poisoned 0xAA -> base 0xAAAAAAAA)

  // ---- setup scratch aliased inside hbuf1 (dead until layer-1 epilogue) ----
  int*   Sint = (int*)hbuf1;
  int*   cnt  = Sint;                    // [1600]
  int*   cur  = Sint + 1600;             // [1600]
  int*   eRec = Sint + 3200;             // [3200]
  float* comb = (float*)(Sint + 6400);   // [256]
  float* red  = (float*)(Sint + 6656);   // [128]   => 27136 B < 54400 B

  // ---- phase 0: stage x -> hbuf0 (f16); zero cnt/cur; msg combined features ----
  for (int i = tid; i < P_ * 32; i += 512) {
    int row = i >> 5, c4 = i & 31;
    const float4 v = ((const float4*)x)[(g * P_ + row) * 32 + c4];
    f16x4 pk = { (_Float16)v.x, (_Float16)v.y, (_Float16)v.z, (_Float16)v.w };
    *((f16x4*)&hbuf0[row * HROW + c4 * 4]) = pk;
  }
  for (int i = tid; i < NKEY; i += 512) { cnt[i] = 0; cur[i] = 0; }
  if (tid < F_) {
    int tok = (int)message[g * 2];
    float cont = message[g * 2 + 1];
    comb[tid] = embed[tok * F_ + tid];
    float ce = cont * cw[tid] + cb[tid];
    comb[F_ + tid] = ce > 0.0f ? ce : 0.0f;
  }
  __syncthreads();

  // ---- phase 1 (wave-specialized): edge ingest || message matmul ----
  int base = g * EPG, nbase = g * P_;
  if (wave < 6) {
    for (int e = wave * 64 + lane; e < EPG; e += 384) {
      int s = ei[base + e] - nbase;
      int d = ei[E_ + base + e] - nbase;
      int r = et[base + e];
      eRec[e] = s | (d << 8) | (r << 16);
      atomicAdd(&cnt[r * P_ + d], 1);
    }
  } else {
    int col = tid & 127;
    float acc = 0.0f;
#pragma unroll 16
    for (int k2 = 0; k2 < 256; k2++) acc += comb[k2] * mw[k2 * F_ + col];
    red[col] = acc;
  }
  __syncthreads();

  // ---- phase 2: wave0 = offset scan (shfl); wave1 = msg finalize ----
  if (wave == 0) {
    int4 vv[8];
    int osum = 0;
    if (lane < 50) {
      const int4* cp = (const int4*)(cnt + lane * 32);
#pragma unroll
      for (int i = 0; i < 8; i++) { vv[i] = cp[i]; osum += vv[i].x + vv[i].y + vv[i].z + vv[i].w; }
    }
    int incl = osum;
#pragma unroll
    for (int d = 1; d < 64; d <<= 1) {
      int t2 = __shfl_up(incl, d, 64);
      if (lane >= d) incl += t2;
    }
    int run = incl - osum;   // exclusive prefix
    if (lane < 50) {
#pragma unroll
      for (int i = 0; i < 8; i++) {
        offsS[lane * 32 + i * 4 + 0] = run; run += vv[i].x;
        offsS[lane * 32 + i * 4 + 1] = run; run += vv[i].y;
        offsS[lane * 32 + i * 4 + 2] = run; run += vv[i].z;
        offsS[lane * 32 + i * 4 + 3] = run; run += vv[i].w;
      }
    }
    if (lane == 0) offsS[NKEY] = EPG;
  } else if (wave == 1) {
    float m0 = mb[lane] + red[lane];
    float m1 = mb[lane + 64] + red[lane + 64];
    m0 = m0 > 0.0f ? m0 : 0.0f;
    m1 = m1 > 0.0f ? m1 : 0.0f;
    msgS[lane] = m0; msgS[lane + 64] = m1;
    float p = m0 * b2[lane] + m1 * b2[lane + 64];
#pragma unroll
    for (int d = 32; d > 0; d >>= 1) p += __shfl_xor(p, d, 64);
    if (lane == 0) msgS[F_] = p;
  }
  __syncthreads();

  // ---- phase 3: CSR scatter from LDS records ----
  for (int e = tid; e < EPG; e += 512) {
    int rec = eRec[e];
    int s = rec & 255, d = (rec >> 8) & 255, r = rec >> 16;
    int key = r * P_ + d;
    int pos = atomicAdd(&cur[key], 1);
    csrS[offsS[key] + pos] = (unsigned short)s;
  }
  // ---- wait for all blocks' wfrag slices (overlapped with all setup above) ----
  if (tid == 0) {
    uint32_t target = 0xAAAAAAAAu + (uint32_t)G_;
    while (__hip_atomic_load(wcnt, __ATOMIC_ACQUIRE, __HIP_MEMORY_SCOPE_AGENT) != target)
      __builtin_amdgcn_s_sleep(2);
  }
  __syncthreads();
  __threadfence();   // invalidate caches so wfrag reads are fresh

  // ---- fused layers: wave w owns rows [w*25, w*25+25); no barriers inside r-loop ----
  int jobBase = wave * 25;
  bool rowAct = (m32 < 25);
  int myD = jobBase + m32;
  int ck = kh * 8;
  int rshift = ((wave >> 2) & 1) << 2;   // SIMD-pairing phase stagger (waves w and w+4 share a SIMD)

  for (int l = 0; l < 2; l++) {
    const _Float16* Ap = (l == 0) ? hbuf0 : hbuf1;
    f32x16 acc[4];
#pragma unroll
    for (int nt = 0; nt < 4; nt++)
#pragma unroll
      for (int i = 0; i < 16; i++) acc[nt][i] = 0.0f;
    const _Float16* wl = wf + l * (9 * 8 * 4 * 64 * 8);
    for (int r = 0; r < 9; r++) {
      int rr = (r < 8) ? ((r + rshift) & 7) : 8;   // staggered relation order (sum order-free)
      const _Float16* wr = wl + rr * (8 * 4 * 64 * 8);
      // prefetch nt=0 B-fragments (8 frags, 32 regs) — in flight during gather
      f16x8 Bn[8];
#pragma unroll
      for (int kt = 0; kt < 8; kt++)
        Bn[kt] = *((const f16x8*)(wr + ((kt * 4 + 0) * 64 + lane) * 8));
      f16x8 a[8];
      if (r < 8) {
        int o = 0, n = 0;
        if (rowAct) { int key = rr * P_ + myD; o = offsS[key]; n = offsS[key + 1] - o; }
        f16x8 z = {0, 0, 0, 0, 0, 0, 0, 0};
#pragma unroll
        for (int kt = 0; kt < 8; kt++) a[kt] = z;
        int t = 0;
        for (; t + 2 <= n; t += 2) {       // unroll-2: 16 reads in flight per period
          int s0 = (int)csrS[o + t];
          int s1 = (int)csrS[o + t + 1];
          const _Float16* hp0 = &Ap[s0 * HROW + ck];
          const _Float16* hp1 = &Ap[s1 * HROW + ck];
          f16x8 u0[8], u1[8];
#pragma unroll
          for (int kt = 0; kt < 8; kt++) u0[kt] = *((const f16x8*)(hp0 + kt * 16));
#pragma unroll
          for (int kt = 0; kt < 8; kt++) u1[kt] = *((const f16x8*)(hp1 + kt * 16));
#pragma unroll
          for (int kt = 0; kt < 8; kt++) a[kt] += u0[kt] + u1[kt];
        }
        if (t < n) {
          int s0 = (int)csrS[o + t];
          const _Float16* hp0 = &Ap[s0 * HROW + ck];
#pragma unroll
          for (int kt = 0; kt < 8; kt++) a[kt] += *((const f16x8*)(hp0 + kt * 16));
        }
        float nf = (n > 0) ? 1.0f / (float)n : 0.0f;
        _Float16 nh = (_Float16)nf;
#pragma unroll
        for (int kt = 0; kt < 8; kt++) a[kt] *= nh;
      } else {
        int rowA = jobBase + (rowAct ? m32 : 24);
        const _Float16* hp = &Ap[rowA * HROW + ck];
#pragma unroll
        for (int kt = 0; kt < 8; kt++) a[kt] = *((const f16x8*)(hp + kt * 16));
      }
      // nt-pipelined MFMA: load nt+1's B under nt's MFMAs (peak 64 B-regs live)
#pragma unroll
      for (int nt = 0; nt < 4; nt++) {
        f16x8 Bx[8];
        if (nt < 3) {
#pragma unroll
          for (int kt = 0; kt < 8; kt++)
            Bx[kt] = *((const f16x8*)(wr + ((kt * 4 + nt + 1) * 64 + lane) * 8));
        }
#pragma unroll
        for (int kt = 0; kt < 8; kt++)
          acc[nt] = __builtin_amdgcn_mfma_f32_32x32x16_f16(a[kt], Bn[kt], acc[nt], 0, 0, 0);
        if (nt < 3) {
#pragma unroll
          for (int kt = 0; kt < 8; kt++) Bn[kt] = Bx[kt];
        }
      }
    }
    if (l == 0) {
      __syncthreads();   // layer-1 MFMA readers of hbuf0 done; hbuf1 scratch dead
      // h' = relu(acc + b1) -> hbuf1; C layout: col=lane&31, row=(reg&3)+8*(reg>>2)+4*kh
#pragma unroll
      for (int nt = 0; nt < 4; nt++) {
        int col = nt * 32 + m32;
        float bias = b1[col];
#pragma unroll
        for (int reg = 0; reg < 16; reg++) {
          int row = (reg & 3) + 8 * (reg >> 2) + 4 * kh;
          if (row < 25) {
            float v = acc[nt][reg] + bias;
            v = v > 0.0f ? v : 0.0f;
            hbuf1[(jobBase + row) * HROW + col] = (_Float16)v;
          }
        }
      }
      __syncthreads();   // h' complete before layer-2 gathers
    } else {
      // score = dot(node_emb, msg) + dot(b2, msg); reduce over 32 col-lanes per half
      float db2 = msgS[F_];
#pragma unroll
      for (int reg = 0; reg < 16; reg++) {
        int row = (reg & 3) + 8 * (reg >> 2) + 4 * kh;
        float p = 0.0f;
#pragma unroll
        for (int nt = 0; nt < 4; nt++)
          p += acc[nt][reg] * msgS[nt * 32 + m32];
        p += __shfl_xor(p, 16, 32);
        p += __shfl_xor(p, 8, 32);
        p += __shfl_xor(p, 4, 32);
        p += __shfl_xor(p, 2, 32);
        p += __shfl_xor(p, 1, 32);
        if (m32 == 0 && row < 25)
          out[g * P_ + jobBase + row] = p + db2;
      }
    }
  }
}

extern "C" void kernel_launch(void* const* d_in, const int* in_sizes, int n_in,
                              void* d_out, int out_size, void* d_ws, size_t ws_size,
                              hipStream_t stream) {
  const float* message = (const float*)d_in[0];
  const float* x       = (const float*)d_in[1];
  const int*   ei      = (const int*)d_in[2];
  const int*   et      = (const int*)d_in[3];
  const float* W1      = (const float*)d_in[6];
  const float* root1   = (const float*)d_in[7];
  const float* b1      = (const float*)d_in[8];
  const float* W2      = (const float*)d_in[9];
  const float* root2   = (const float*)d_in[10];
  const float* b2      = (const float*)d_in[11];
  const float* embed   = (const float*)d_in[12];
  const float* cw      = (const float*)d_in[13];
  const float* cb      = (const float*)d_in[14];
  const float* mw      = (const float*)d_in[15];
  const float* mb      = (const float*)d_in[16];

  _Float16* wfrag = (_Float16*)d_ws;                      // 589,824 B
  uint32_t* wcnt  = (uint32_t*)((char*)d_ws + 589824);    // 4 B, poisoned to 0xAAAAAAAA
  float*    out   = (float*)d_out;

  hipLaunchKernelGGL(k_main, dim3(G_), dim3(512), 0, stream, x, ei, et,
                     W1, root1, W2, root2, b1, b2,
                     message, embed, cw, cb, mw, mb, wfrag, wcnt, out);
}

// Round 9
// 176.500 us; speedup vs baseline: 1.4565x; 1.4565x over previous
//
#include <hip/hip_runtime.h>
#include <stdint.h>

#define G_   250
#define P_   200
#define EPG  3200
#define E_   800000
#define F_   128
#define R_   8
#define HROW 136   // f16 elems per row; 272 B stride, 16B-aligned rows
#define NKEY (R_ * P_)   // 1600 (rel,dst) buckets
#define BSTG (8 * 4 * 64 * 8)   // 16384 f16 = 32 KB per (l,r) B-fragment set

typedef _Float16 f16x8 __attribute__((ext_vector_type(8)));
typedef _Float16 f16x4 __attribute__((ext_vector_type(4)));
typedef float    f32x4 __attribute__((ext_vector_type(4)));
typedef float    f32x16 __attribute__((ext_vector_type(16)));

// ---------------- prepass: W -> B-fragment layout for mfma_f32_32x32x16_f16 ----------------
// layout: flat = ((((l*9+r)*8 + kt)*4 + ntj)*64 + lane)*8 + j
//         value = W[r][k = kt*16 + (lane>>5)*8 + j][n = ntj*32 + (lane&31)]  (r==8 -> root)
__global__ __launch_bounds__(256) void k_wstage(const float* __restrict__ W1, const float* __restrict__ root1,
                                                const float* __restrict__ W2, const float* __restrict__ root2,
                                                _Float16* __restrict__ wf) {
  int t = blockIdx.x * 256 + threadIdx.x;    // exactly 1152*256 = 2*9*128*128
  int n = t & 127;
  int k = (t >> 7) & 127;
  int rl_ = t >> 14;          // 0..17
  int r = rl_ % 9, l = rl_ / 9;
  const float* Wl = (l == 0) ? W1 : W2;
  const float* rt = (l == 0) ? root1 : root2;
  float v = (r < 8) ? Wl[(r * F_ + k) * F_ + n] : rt[k * F_ + n];
  int lane = (n & 31) | (((k >> 3) & 1) << 5);
  int j = k & 7, kt = k >> 4, ntj = n >> 5;
  wf[((((l * 9 + r) * 8 + kt) * 4 + ntj) * 64 + lane) * 8 + j] = (_Float16)v;
}

// ---------------- main: one workgroup = one graph; LDS-staged B, 8 waves x 25-row jobs --------
__global__ __launch_bounds__(512, 1) void k_main(
    const float* __restrict__ x, const int* __restrict__ ei, const int* __restrict__ et,
    const _Float16* __restrict__ wf, const float* __restrict__ b1, const float* __restrict__ b2,
    const float* __restrict__ message, const float* __restrict__ embed,
    const float* __restrict__ cw, const float* __restrict__ cb,
    const float* __restrict__ mw, const float* __restrict__ mb,
    float* __restrict__ out) {
  __shared__ __attribute__((aligned(16))) _Float16 hbuf0[P_ * HROW];  // 54400 B
  __shared__ __attribute__((aligned(16))) _Float16 hbuf1[P_ * HROW];  // 54400 B
  __shared__ __attribute__((aligned(16))) _Float16 Bstage[BSTG];      // 32768 B
  __shared__ unsigned short csrS[EPG];                                // 6400 B
  __shared__ int offsS[NKEY + 1];                                     // 6404 B
  __shared__ float msgS[F_ + 1];                                      // 516 B  -> 154888 B

  int g = blockIdx.x, tid = threadIdx.x;
  int lane = tid & 63, wave = tid >> 6;
  int m32 = lane & 31, kh = lane >> 5;

  // ---- setup scratch aliased inside hbuf1 (dead until layer-1 epilogue) ----
  int*   Sint = (int*)hbuf1;
  int*   cnt  = Sint;                    // [1600]
  int*   cur  = Sint + 1600;             // [1600]
  int*   eRec = Sint + 3200;             // [3200]
  float* comb = (float*)(Sint + 6400);   // [256]
  float* red  = (float*)(Sint + 6656);   // [128]   => 27136 B < 54400 B

  // ---- phase 0: stage x -> hbuf0 (f16); zero cnt/cur; msg combined features ----
  for (int i = tid; i < P_ * 32; i += 512) {
    int row = i >> 5, c4 = i & 31;
    const float4 v = ((const float4*)x)[(g * P_ + row) * 32 + c4];
    f16x4 pk = { (_Float16)v.x, (_Float16)v.y, (_Float16)v.z, (_Float16)v.w };
    *((f16x4*)&hbuf0[row * HROW + c4 * 4]) = pk;
  }
  for (int i = tid; i < NKEY; i += 512) { cnt[i] = 0; cur[i] = 0; }
  if (tid < F_) {
    int tok = (int)message[g * 2];
    float cont = message[g * 2 + 1];
    comb[tid] = embed[tok * F_ + tid];
    float ce = cont * cw[tid] + cb[tid];
    comb[F_ + tid] = ce > 0.0f ? ce : 0.0f;
  }
  __syncthreads();

  // ---- phase 1 (wave-specialized): edge ingest || message matmul ----
  int base = g * EPG, nbase = g * P_;
  if (wave < 6) {
    for (int e = wave * 64 + lane; e < EPG; e += 384) {
      int s = ei[base + e] - nbase;
      int d = ei[E_ + base + e] - nbase;
      int r = et[base + e];
      eRec[e] = s | (d << 8) | (r << 16);
      atomicAdd(&cnt[r * P_ + d], 1);
    }
  } else {
    int col = tid & 127;
    float acc = 0.0f;
#pragma unroll 16
    for (int k2 = 0; k2 < 256; k2++) acc += comb[k2] * mw[k2 * F_ + col];
    red[col] = acc;
  }
  __syncthreads();

  // ---- phase 2: wave0 = offset scan (shfl); wave1 = msg finalize ----
  if (wave == 0) {
    int4 vv[8];
    int osum = 0;
    if (lane < 50) {
      const int4* cp = (const int4*)(cnt + lane * 32);
#pragma unroll
      for (int i = 0; i < 8; i++) { vv[i] = cp[i]; osum += vv[i].x + vv[i].y + vv[i].z + vv[i].w; }
    }
    int incl = osum;
#pragma unroll
    for (int d = 1; d < 64; d <<= 1) {
      int t2 = __shfl_up(incl, d, 64);
      if (lane >= d) incl += t2;
    }
    int run = incl - osum;   // exclusive prefix
    if (lane < 50) {
#pragma unroll
      for (int i = 0; i < 8; i++) {
        offsS[lane * 32 + i * 4 + 0] = run; run += vv[i].x;
        offsS[lane * 32 + i * 4 + 1] = run; run += vv[i].y;
        offsS[lane * 32 + i * 4 + 2] = run; run += vv[i].z;
        offsS[lane * 32 + i * 4 + 3] = run; run += vv[i].w;
      }
    }
    if (lane == 0) offsS[NKEY] = EPG;
  } else if (wave == 1) {
    float m0 = mb[lane] + red[lane];
    float m1 = mb[lane + 64] + red[lane + 64];
    m0 = m0 > 0.0f ? m0 : 0.0f;
    m1 = m1 > 0.0f ? m1 : 0.0f;
    msgS[lane] = m0; msgS[lane + 64] = m1;
    float p = m0 * b2[lane] + m1 * b2[lane + 64];
#pragma unroll
    for (int d = 32; d > 0; d >>= 1) p += __shfl_xor(p, d, 64);
    if (lane == 0) msgS[F_] = p;
  }
  __syncthreads();

  // ---- phase 3: CSR scatter from LDS records ----
  for (int e = tid; e < EPG; e += 512) {
    int rec = eRec[e];
    int s = rec & 255, d = (rec >> 8) & 255, r = rec >> 16;
    int key = r * P_ + d;
    int pos = atomicAdd(&cur[key], 1);
    csrS[offsS[key] + pos] = (unsigned short)s;
  }
  __syncthreads();   // hbuf0 + csr + offs + msg ready; hbuf1 scratch dead; Bstage free

  // ---- fused layers: wave w owns rows [w*25, w*25+25); B staged through LDS per (l,r) ----
  int jobBase = wave * 25;
  bool rowAct = (m32 < 25);
  int myD = jobBase + m32;
  int ck = kh * 8;

  for (int l = 0; l < 2; l++) {
    const _Float16* Ap = (l == 0) ? hbuf0 : hbuf1;
    f32x16 acc[4];
#pragma unroll
    for (int nt = 0; nt < 4; nt++)
#pragma unroll
      for (int i = 0; i < 16; i++) acc[nt][i] = 0.0f;
    const _Float16* wl = wf + l * (9 * BSTG);
    for (int r = 0; r < 9; r++) {
      const _Float16* wr = wl + r * BSTG;
      // B-stage loads: thread tid covers 4x16B, dense 8KB rounds (coalesced, L2-resident);
      // issued BEFORE the gather so they fly under it.
      f16x8 st[4];
#pragma unroll
      for (int i = 0; i < 4; i++)
        st[i] = *((const f16x8*)(wr + i * 4096 + tid * 8));
      // gather this lane's A rows for relation r (unroll-2)
      f16x8 a[8];
      if (r < 8) {
        int o = 0, n = 0;
        if (rowAct) { int key = r * P_ + myD; o = offsS[key]; n = offsS[key + 1] - o; }
        f16x8 z = {0, 0, 0, 0, 0, 0, 0, 0};
#pragma unroll
        for (int kt = 0; kt < 8; kt++) a[kt] = z;
        int t = 0;
        for (; t + 2 <= n; t += 2) {
          int s0 = (int)csrS[o + t];
          int s1 = (int)csrS[o + t + 1];
          const _Float16* hp0 = &Ap[s0 * HROW + ck];
          const _Float16* hp1 = &Ap[s1 * HROW + ck];
          f16x8 u0[8], u1[8];
#pragma unroll
          for (int kt = 0; kt < 8; kt++) u0[kt] = *((const f16x8*)(hp0 + kt * 16));
#pragma unroll
          for (int kt = 0; kt < 8; kt++) u1[kt] = *((const f16x8*)(hp1 + kt * 16));
#pragma unroll
          for (int kt = 0; kt < 8; kt++) a[kt] += u0[kt] + u1[kt];
        }
        if (t < n) {
          int s0 = (int)csrS[o + t];
          const _Float16* hp0 = &Ap[s0 * HROW + ck];
#pragma unroll
          for (int kt = 0; kt < 8; kt++) a[kt] += *((const f16x8*)(hp0 + kt * 16));
        }
        float nf = (n > 0) ? 1.0f / (float)n : 0.0f;
        _Float16 nh = (_Float16)nf;
#pragma unroll
        for (int kt = 0; kt < 8; kt++) a[kt] *= nh;
      } else {
        int rowA = jobBase + (rowAct ? m32 : 24);
        const _Float16* hp = &Ap[rowA * HROW + ck];
#pragma unroll
        for (int kt = 0; kt < 8; kt++) a[kt] = *((const f16x8*)(hp + kt * 16));
      }
      // write staged B to LDS
#pragma unroll
      for (int i = 0; i < 4; i++)
        *((f16x8*)(Bstage + i * 4096 + tid * 8)) = st[i];
      __syncthreads();   // Bstage r visible
      // MFMA phase: B-frags from LDS (conflict-free lane-dense b128)
#pragma unroll
      for (int nt = 0; nt < 4; nt++) {
#pragma unroll
        for (int kt = 0; kt < 8; kt++) {
          f16x8 b = *((const f16x8*)&Bstage[((kt * 4 + nt) * 64 + lane) * 8]);
          acc[nt] = __builtin_amdgcn_mfma_f32_32x32x16_f16(a[kt], b, acc[nt], 0, 0, 0);
        }
      }
      __syncthreads();   // all waves done reading Bstage before next r overwrites
    }
    if (l == 0) {
      // h' = relu(acc + b1) -> hbuf1; C layout: col=lane&31, row=(reg&3)+8*(reg>>2)+4*kh
#pragma unroll
      for (int nt = 0; nt < 4; nt++) {
        int col = nt * 32 + m32;
        float bias = b1[col];
#pragma unroll
        for (int reg = 0; reg < 16; reg++) {
          int row = (reg & 3) + 8 * (reg >> 2) + 4 * kh;
          if (row < 25) {
            float v = acc[nt][reg] + bias;
            v = v > 0.0f ? v : 0.0f;
            hbuf1[(jobBase + row) * HROW + col] = (_Float16)v;
          }
        }
      }
      __syncthreads();   // h' complete before layer-2 gathers
    } else {
      // score = dot(node_emb, msg) + dot(b2, msg)
      float db2 = msgS[F_];
#pragma unroll
      for (int reg = 0; reg < 16; reg++) {
        int row = (reg & 3) + 8 * (reg >> 2) + 4 * kh;
        float p = 0.0f;
#pragma unroll
        for (int nt = 0; nt < 4; nt++)
          p += acc[nt][reg] * msgS[nt * 32 + m32];
        p += __shfl_xor(p, 16, 32);
        p += __shfl_xor(p, 8, 32);
        p += __shfl_xor(p, 4, 32);
        p += __shfl_xor(p, 2, 32);
        p += __shfl_xor(p, 1, 32);
        if (m32 == 0 && row < 25)
          out[g * P_ + jobBase + row] = p + db2;
      }
    }
  }
}

extern "C" void kernel_launch(void* const* d_in, const int* in_sizes, int n_in,
                              void* d_out, int out_size, void* d_ws, size_t ws_size,
                              hipStream_t stream) {
  const float* message = (const float*)d_in[0];
  const float* x       = (const float*)d_in[1];
  const int*   ei      = (const int*)d_in[2];
  const int*   et      = (const int*)d_in[3];
  const float* W1      = (const float*)d_in[6];
  const float* root1   = (const float*)d_in[7];
  const float* b1      = (const float*)d_in[8];
  const float* W2      = (const float*)d_in[9];
  const float* root2   = (const float*)d_in[10];
  const float* b2      = (const float*)d_in[11];
  const float* embed   = (const float*)d_in[12];
  const float* cw      = (const float*)d_in[13];
  const float* cb      = (const float*)d_in[14];
  const float* mw      = (const float*)d_in[15];
  const float* mb      = (const float*)d_in[16];

  _Float16* wfrag = (_Float16*)d_ws;   // 589,824 B
  float*    out   = (float*)d_out;

  hipLaunchKernelGGL(k_wstage, dim3(1152), dim3(256), 0, stream, W1, root1, W2, root2, wfrag);
  hipLaunchKernelGGL(k_main, dim3(G_), dim3(512), 0, stream, x, ei, et, wfrag, b1, b2,
                     message, embed, cw, cb, mw, mb, out);
}